// Round 1
// 930.067 us; speedup vs baseline: 1.1227x; 1.1227x over previous
//
#include <hip/hip_runtime.h>
#include <math.h>

#define NN 200000
#define BB 300
#define KK 10
#define DD 172
#define R0T 9900        // layer-0 rows: 900 targets + 9000 hop-1 centers
#define R0P 9984        // padded to 128
#define L1P 1024        // 900 padded
#define QIN_K 384       // 344 padded
#define KIN_K 576       // 516 padded (merge A width)
#define H_K 192         // 172 padded
#define CK 1088         // 2*516 padded to 64-mult (c-vector / Mcat K)
#define QKN 1034        // qk cols: 2*516 + 2 qbk cols
#define QKLD 1040
#define GROWS 1152      // Gcat Bt rows (9 tiles)
#define KINLD 552       // kin LDS row stride (shorts); 552*2=1104B, 276dw%32=20 -> b128 conflict-free

typedef short bfrag __attribute__((ext_vector_type(8)));
typedef float f4 __attribute__((ext_vector_type(4)));
typedef unsigned short us4 __attribute__((ext_vector_type(4)));

__device__ inline unsigned short f2b(float f) {
  unsigned int u = __builtin_bit_cast(unsigned int, f);
  u += 0x7fffu + ((u >> 16) & 1u);
  return (unsigned short)(u >> 16);
}
__device__ inline float b2f(unsigned short s) {
  unsigned int u = ((unsigned int)s) << 16;
  return __builtin_bit_cast(float, u);
}
__device__ inline float sigm(float x) { return 1.f / (1.f + expf(-x)); }

// ---------------- map ----------------
__global__ __launch_bounds__(256) void fill_map(int* map) {
  int i = blockIdx.x * 256 + threadIdx.x;
  if (i < NN) map[i] = -1;
}
__global__ __launch_bounds__(64) void set_map(int* map, const int* src, const int* dst) {
  int i = blockIdx.x * 64 + threadIdx.x;
  if (i < BB) { map[src[i]] = i; map[dst[i]] = BB + i; }
}

// ---------------- bf16 weight prep (slices/transposes, zero-padded) ----------------
#define SZ_WQH (2*2*384*192)
#define SZ_WKH (2*2*640*192)
#define SZ_WVH (2*2*640*192)
#define SZ_WOT (2*2*384*192)
#define SZ_M1  (2*256*576)
#define SZ_M2  (2*256*192)
#define SZ_MW1 (384*704)
#define SZ_MW2 (128*384)
#define SZ_GIH (640*128)
#define SZ_GHH (640*192)
__global__ __launch_bounds__(256) void prep_w(
    const float* wq, const float* wk, const float* wv, const float* wo,
    const float* m1, const float* m2, const float* mw1, const float* mw2,
    const float* gih, const float* ghh,
    unsigned short* wqh_b, unsigned short* wkh_b, unsigned short* wvh_b,
    unsigned short* woT_b, unsigned short* wm1_t, unsigned short* wm2_t,
    unsigned short* msgw1t, unsigned short* msgw2t,
    unsigned short* gruwih_b, unsigned short* gruwhh_b) {
  long idx = (long)blockIdx.x * 256 + threadIdx.x;
  if (idx < SZ_WQH) {  // wqh_b[l][h][y<384][d<192] = Wq[l][y][h*172+d]
    int l = idx / (2*384*192), r = idx % (2*384*192);
    int h = r / (384*192); r %= 384*192;
    int y = r / 192, d = r % 192;
    wqh_b[idx] = (y < 344 && d < 172) ? f2b(wq[(size_t)l*344*344 + (size_t)y*344 + h*172 + d]) : 0;
    return;
  }
  idx -= SZ_WQH;
  if (idx < SZ_WKH) {  // wkh_b[l][h][x<640][d<192] = Wk[l][x][h*172+d]
    int l = idx / (2*640*192), r = idx % (2*640*192);
    int h = r / (640*192); r %= 640*192;
    int x = r / 192, d = r % 192;
    wkh_b[idx] = (x < 516 && d < 172) ? f2b(wk[(size_t)l*516*344 + (size_t)x*344 + h*172 + d]) : 0;
    return;
  }
  idx -= SZ_WKH;
  if (idx < SZ_WVH) {
    int l = idx / (2*640*192), r = idx % (2*640*192);
    int h = r / (640*192); r %= 640*192;
    int x = r / 192, d = r % 192;
    wvh_b[idx] = (x < 516 && d < 172) ? f2b(wv[(size_t)l*516*344 + (size_t)x*344 + h*172 + d]) : 0;
    return;
  }
  idx -= SZ_WVH;
  if (idx < SZ_WOT) {  // woT_b[l][h][j<384][d<192] = Wo[l][h*172+d][j]
    int l = idx / (2*384*192), r = idx % (2*384*192);
    int h = r / (384*192); r %= 384*192;
    int j = r / 192, d = r % 192;
    woT_b[idx] = (j < 344 && d < 172) ? f2b(wo[(size_t)l*344*344 + (size_t)(h*172+d)*344 + j]) : 0;
    return;
  }
  idx -= SZ_WOT;
  if (idx < SZ_M1) {  // wm1_t[l][j<256][k<576] = m1[l][k][j]
    int l = idx / (256*576), r = idx % (256*576);
    int j = r / 576, k = r % 576;
    wm1_t[idx] = (j < 172 && k < 516) ? f2b(m1[(size_t)l*516*172 + (size_t)k*172 + j]) : 0;
    return;
  }
  idx -= SZ_M1;
  if (idx < SZ_M2) {  // wm2_t[l][j<256][k<192] = m2[l][k][j]
    int l = idx / (256*192), r = idx % (256*192);
    int j = r / 192, k = r % 192;
    wm2_t[idx] = (j < 172 && k < 172) ? f2b(m2[(size_t)l*172*172 + (size_t)k*172 + j]) : 0;
    return;
  }
  idx -= SZ_M2;
  if (idx < SZ_MW1) {  // msgw1t[j<384][k<704] = mw1[k][j]
    int j = idx / 704, k = idx % 704;
    msgw1t[idx] = (j < 344 && k < 689) ? f2b(mw1[(size_t)k*344 + j]) : 0;
    return;
  }
  idx -= SZ_MW1;
  if (idx < SZ_MW2) {  // msgw2t[j<128][k<384] = mw2[k][j]
    int j = idx / 384, k = idx % 384;
    msgw2t[idx] = (j < 100 && k < 344) ? f2b(mw2[(size_t)k*100 + j]) : 0;
    return;
  }
  idx -= SZ_MW2;
  if (idx < SZ_GIH) {  // gruwih_b[j<640][k<128] = gih[j][k]
    int j = idx / 128, k = idx % 128;
    gruwih_b[idx] = (j < 516 && k < 100) ? f2b(gih[(size_t)j*100 + k]) : 0;
    return;
  }
  idx -= SZ_GIH;
  if (idx < SZ_GHH) {  // gruwhh_b[j<640][k<192] = ghh[j][k]
    int j = idx / 192, k = idx % 192;
    gruwhh_b[idx] = (j < 516 && k < 172) ? f2b(ghh[(size_t)j*172 + k]) : 0;
    return;
  }
}

// fp32 bias folds + gvec rows of Gcat + cos(time_b) table
#define SB_QK (2*QKLD)
#define SB_VO (2*344)
#define SB_GV (2*2*384)
#define SB_CT 176
__global__ __launch_bounds__(256) void prep_bias(
    const float* wq, const float* wk, const float* wo,
    const float* bq, const float* bk, const float* bv, const float* bo,
    const float* time_b,
    float* bqk, float* bvwo, unsigned short* Gcat, unsigned short* costb) {
  long idx = (long)blockIdx.x * 256 + threadIdx.x;
  if (idx < SB_QK) {
    int l = idx / QKLD, x = idx % QKLD;
    float acc = 0.f;
    if (x < 1032) {
      int h = x / 516, xx = x % 516;
      for (int d = 0; d < 172; d++)
        acc += wk[(size_t)l*516*344 + (size_t)xx*344 + h*172 + d] * bq[(size_t)l*344 + h*172 + d];
    } else if (x < 1034) {
      int h = x - 1032;
      for (int d = 0; d < 172; d++)
        acc += bq[(size_t)l*344 + h*172 + d] * bk[(size_t)l*344 + h*172 + d];
    }
    bqk[idx] = acc;
    return;
  }
  idx -= SB_QK;
  if (idx < SB_VO) {
    int l = idx / 344, j = idx % 344;
    float acc = bo[(size_t)l*344 + j];
    for (int c = 0; c < 344; c++)
      acc += bv[(size_t)l*344 + c] * wo[(size_t)l*344*344 + (size_t)c*344 + j];
    bvwo[idx] = acc;
    return;
  }
  idx -= SB_VO;
  if (idx < SB_GV) {
    int l = idx / (2*384), r = idx % (2*384);
    int h = r / 384, y = r % 384;
    float acc = 0.f;
    if (y < 344)
      for (int d = 0; d < 172; d++)
        acc += wq[(size_t)l*344*344 + (size_t)y*344 + h*172 + d] * bk[(size_t)l*344 + h*172 + d];
    Gcat[(size_t)l*GROWS*384 + (size_t)(1032+h)*384 + y] = (y < 344) ? f2b(acc) : 0;
    return;
  }
  idx -= SB_GV;
  if (idx < SB_CT) {
    costb[idx] = (idx < 172) ? f2b(cosf(time_b[idx])) : 0;
    return;
  }
}

// ---------------- 128x128 bf16 MFMA GEMM: C = A[MxKpad] @ Bt[NxKpad]^T + bias ----------------
template<bool OBF, bool RELU>
__global__ __launch_bounds__(256) void gemm128(
    const unsigned short* __restrict__ A, int lda,
    const unsigned short* __restrict__ Bt, int ldb,
    const float* __restrict__ bias,
    void* __restrict__ Cv, int ldc, int M, int N, int Nz, int Kpad) {
  __shared__ __align__(16) unsigned short As[128][72];
  __shared__ __align__(16) unsigned short Bs[128][72];
  const int tid = threadIdx.x;
  const int lane = tid & 63, w = tid >> 6;
  const int rbase = (w >> 1) * 64, cbase = (w & 1) * 64;
  const int fr = lane & 15, fq = lane >> 4;
  const size_t Arow0 = (size_t)blockIdx.x * 128;
  const size_t Brow0 = (size_t)blockIdx.y * 128;
  f4 acc[4][4];
#pragma unroll
  for (int a = 0; a < 4; a++)
#pragma unroll
    for (int b = 0; b < 4; b++)
#pragma unroll
      for (int r = 0; r < 4; r++) acc[a][b][r] = 0.f;

  const int srow = tid >> 3, sch = tid & 7;
  for (int k0 = 0; k0 < Kpad; k0 += 64) {
#pragma unroll
    for (int p = 0; p < 4; p++) {
      int row = srow + p * 32;
      *(uint4*)&As[row][sch * 8] = *(const uint4*)(A + (Arow0 + row) * lda + k0 + sch * 8);
      *(uint4*)&Bs[row][sch * 8] = *(const uint4*)(Bt + (Brow0 + row) * ldb + k0 + sch * 8);
    }
    __syncthreads();
#pragma unroll
    for (int s = 0; s < 2; s++) {
      bfrag a[4], b[4];
#pragma unroll
      for (int mt = 0; mt < 4; mt++) a[mt] = *(const bfrag*)&As[rbase + mt*16 + fr][s*32 + fq*8];
#pragma unroll
      for (int nt = 0; nt < 4; nt++) b[nt] = *(const bfrag*)&Bs[cbase + nt*16 + fr][s*32 + fq*8];
#pragma unroll
      for (int mt = 0; mt < 4; mt++)
#pragma unroll
        for (int nt = 0; nt < 4; nt++)
          acc[mt][nt] = __builtin_amdgcn_mfma_f32_16x16x32_bf16(a[mt], b[nt], acc[mt][nt], 0, 0, 0);
    }
    __syncthreads();
  }
#pragma unroll
  for (int mt = 0; mt < 4; mt++) {
#pragma unroll
    for (int nt = 0; nt < 4; nt++) {
      int gc = (int)Brow0 + cbase + nt * 16 + fr;
      float bias_v = (bias != nullptr && gc < N) ? bias[gc] : 0.f;
#pragma unroll
      for (int r = 0; r < 4; r++) {
        int gr = (int)Arow0 + rbase + mt * 16 + fq * 4 + r;
        if (gr < M && gc < Nz) {
          float v = 0.f;
          if (gc < N) {
            v = acc[mt][nt][r] + bias_v;
            if (RELU) v = fmaxf(v, 0.f);
          }
          if (OBF) ((unsigned short*)Cv)[(size_t)gr * ldc + gc] = f2b(v);
          else     ((float*)Cv)[(size_t)gr * ldc + gc] = v;
        }
      }
    }
  }
}

// ---------------- message phase ----------------
__global__ __launch_bounds__(256) void build_raw(
    const float* memory, const float* edge_features, const float* last_update,
    const float* time_w, const float* time_b,
    const float* num_w1, const float* num_b1, const float* num_w2, const float* num_b2,
    const float* edge_times, const float* num_conn,
    const int* src, const int* dst, const int* edge_idxs,
    unsigned short* raw, unsigned short* memb) {
  const int r = blockIdx.x, t = threadIdx.x;
  const int e = (r < BB) ? r : r - BB;
  const int a = (r < BB) ? src[e] : dst[e];
  const int b = (r < BB) ? dst[e] : src[e];
  const int ei = edge_idxs[e];
  const float dt = edge_times[e] - last_update[a];
  for (int c = t; c < 704; c += 256) {
    float v;
    if (c < 172) v = memory[(size_t)a*DD + c];
    else if (c < 344) v = memory[(size_t)b*DD + (c-172)];
    else if (c < 516) v = edge_features[(size_t)ei*DD + (c-344)];
    else if (c < 688) { int d = c-516; v = cosf(dt * time_w[d] + time_b[d]); }
    else if (c == 688) v = fmaxf(num_conn[e]*num_w1[0]+num_b1[0], 0.f)*num_w2[0]+num_b2[0];
    else v = 0.f;
    raw[(size_t)r*704 + c] = f2b(v);
  }
  for (int d = t; d < 192; d += 256)
    memb[(size_t)r*192 + d] = (d < 172) ? f2b(memory[(size_t)a*DD + d]) : 0;
}

__global__ __launch_bounds__(192) void gru_gate(
    const float* gi, const float* gh, const float* memory,
    const int* src, const int* dst, float* upd) {
  int r = blockIdx.x, t = threadIdx.x;
  int a = (r < BB) ? src[r] : dst[r - BB];
  if (t < DD) {
    float i_r = gi[(size_t)r*516 + t], i_z = gi[(size_t)r*516 + DD + t], i_n = gi[(size_t)r*516 + 2*DD + t];
    float h_r = gh[(size_t)r*516 + t], h_z = gh[(size_t)r*516 + DD + t], h_n = gh[(size_t)r*516 + 2*DD + t];
    float rr = sigm(i_r + h_r);
    float z  = sigm(i_z + h_z);
    float nn = tanhf(i_n + rr * h_n);
    float h  = memory[(size_t)a*DD + t];
    upd[(size_t)r*DD + t] = (1.f - z) * nn + z * h;
  }
}

// ---------------- q_in builders (vectorized) ----------------
__global__ __launch_bounds__(128) void build_qin0(
    const int* src, const int* dst, const int* neg, const int* n1_nb,
    const float* memory, const float* upd, const int* map, const float* nf,
    const unsigned short* costb, unsigned short* qin) {
  const int i = blockIdx.x, t = threadIdx.x;
  if (t >= 96) return;
  const int node = (i < BB) ? src[i] : (i < 2*BB) ? dst[i-BB] : (i < 3*BB) ? neg[i-2*BB] : n1_nb[i-3*BB];
  unsigned short* row = qin + (size_t)i * QIN_K;
  if (t < 43) {
    const int m = map[node];
    const float* mrow = (m >= 0) ? upd + (size_t)m*DD : memory + (size_t)node*DD;
    const int c = t * 4;
    f4 a = *(const f4*)(mrow + c);
    f4 b = *(const f4*)(nf + (size_t)node*DD + c);
    us4 o;
    o[0] = f2b(a[0]+b[0]); o[1] = f2b(a[1]+b[1]); o[2] = f2b(a[2]+b[2]); o[3] = f2b(a[3]+b[3]);
    *(us4*)(row + c) = o;
  } else if (t < 86) {
    const int c = (t - 43) * 4;
    *(us4*)(row + 172 + c) = *(const us4*)(costb + c);
  } else {
    us4 z = {0,0,0,0};
    *(us4*)(row + 344 + (t - 86) * 4) = z;
  }
}

__global__ __launch_bounds__(128) void build_qin1(
    const unsigned short* conv0, const unsigned short* costb, unsigned short* qin1) {
  const int i = blockIdx.x, t = threadIdx.x;
  if (t >= 96) return;
  unsigned short* row = qin1 + (size_t)i * QIN_K;
  if (t < 43) {
    const int c = t * 4;
    *(us4*)(row + c) = *(const us4*)(conv0 + (size_t)i*DD + c);
  } else if (t < 86) {
    const int c = (t - 43) * 4;
    *(us4*)(row + 172 + c) = *(const us4*)(costb + c);
  } else {
    us4 z = {0,0,0,0};
    *(us4*)(row + 344 + (t - 86) * 4) = z;
  }
}

// ---------------- fused per-node attention core (vectorized + MFMA scores) ----------------
// featb: bf16 feature rows for neighbors when available (MODE0 i<3BB: qin0; MODE1: conv0)
template <int MODE>
__global__ __launch_bounds__(256) void attn_core(
    const unsigned short* __restrict__ qk,   // [n][QKLD] bf16
    const int* n1_nb, const int* n1_ei, const float* n1_et,
    const int* n2_nb, const int* n2_ei, const float* n2_et,
    const float* edge_times,
    const float* memory, const float* upd, const int* map, const float* nf,
    const unsigned short* featb, int featld,
    const float* ef, const float* time_w, const float* time_b,
    unsigned short* __restrict__ C) {
  __shared__ __align__(16) unsigned short s_kin[KK][KINLD];
  __shared__ __align__(16) unsigned short s_qkb[2][544];
  __shared__ float s_att[2][16];
  __shared__ float s_qbk[2];
  __shared__ int s_nb[KK];
  __shared__ float s_dt[KK];
  __shared__ const float* s_fr[KK];
  __shared__ const unsigned short* s_br[KK];
  __shared__ const float* s_er[KK];
  const int i = blockIdx.x, t = threadIdx.x;
  const int lane = t & 63, w = t >> 6;
  const bool usebr = (MODE == 1) || (i < 3*BB);

  // ---- phase 1: qk row -> LDS, per-neighbor metadata ----
  for (int u = t; u < 272; u += 256) {
    int h = u / 136, s = u - h * 136;
    us4 v = {0,0,0,0};
    int x;
    if (s < 129) { x = s * 4; v = *(const us4*)(qk + (size_t)i*QKLD + h*516 + x); }
    else x = 516 + (s - 129) * 4;
    *(us4*)&s_qkb[h][x] = v;
  }
  if (t < 2) s_qbk[t] = b2f(qk[(size_t)i*QKLD + 1032 + t]);
  if (t < KK) {
    int nb, ei; float et, ts;
    if (MODE == 0 && i >= 3*BB) {
      int j = i - 3*BB;
      nb = n2_nb[(size_t)j*KK + t]; ei = n2_ei[(size_t)j*KK + t]; et = n2_et[(size_t)j*KK + t];
      ts = edge_times[(j / KK) % BB];
    } else {
      nb = n1_nb[(size_t)i*KK + t]; ei = n1_ei[(size_t)i*KK + t]; et = n1_et[(size_t)i*KK + t];
      ts = edge_times[i % BB];
    }
    s_nb[t] = nb;
    s_dt[t] = ts - et;
    s_er[t] = ef + (size_t)ei * DD;
    if (usebr) {
      s_br[t] = featb + (size_t)(3*BB + i*KK + t) * featld;
    } else {
      int m = map[nb];
      s_fr[t] = (m >= 0) ? upd + (size_t)m * DD : memory + (size_t)nb * DD;
    }
  }
  __syncthreads();

  // ---- phase 2: build k_in rows (segment-major units: 430 feat, 430 ef, 430 cos, 70 pad) ----
  for (int u = t; u < 1360; u += 256) {
    if (u < 430) {
      int k = u / 43, c = (u - k * 43) * 4;
      us4 o;
      if (usebr) {
        o = *(const us4*)(s_br[k] + c);
      } else {
        f4 a = *(const f4*)(s_fr[k] + c);
        f4 b = *(const f4*)(nf + (size_t)s_nb[k] * DD + c);
        o[0] = f2b(a[0]+b[0]); o[1] = f2b(a[1]+b[1]); o[2] = f2b(a[2]+b[2]); o[3] = f2b(a[3]+b[3]);
      }
      *(us4*)&s_kin[k][c] = o;
    } else if (u < 860) {
      int v = u - 430;
      int k = v / 43, c = (v - k * 43) * 4;
      f4 e = *(const f4*)(s_er[k] + c);
      us4 o;
      o[0] = f2b(e[0]); o[1] = f2b(e[1]); o[2] = f2b(e[2]); o[3] = f2b(e[3]);
      *(us4*)&s_kin[k][172 + c] = o;
    } else if (u < 1290) {
      int v = u - 860;
      int k = v / 43, c = (v - k * 43) * 4;
      float dt = s_dt[k];
      f4 wv = *(const f4*)(time_w + c);
      f4 bv = *(const f4*)(time_b + c);
      us4 o;
      o[0] = f2b(cosf(dt*wv[0]+bv[0])); o[1] = f2b(cosf(dt*wv[1]+bv[1]));
      o[2] = f2b(cosf(dt*wv[2]+bv[2])); o[3] = f2b(cosf(dt*wv[3]+bv[3]));
      *(us4*)&s_kin[k][344 + c] = o;
    } else {
      int v = u - 1290;
      int k = v / 7, c = (v - k * 7) * 4;
      us4 z = {0,0,0,0};
      *(us4*)&s_kin[k][516 + c] = z;
    }
  }
  __syncthreads();

  // ---- phase 3: scores + softmax on wave 0 via MFMA ----
  // A row = lane&15 (qk head, rows 2..15 duplicates), B col = lane&15 (kin row, clamped)
  if (w == 0) {
    const unsigned short* arow = s_qkb[lane & 1];
    int bc = lane & 15; bc = (bc > 9) ? 9 : bc;
    const unsigned short* brow = s_kin[bc];
    const int q8 = (lane >> 4) * 8;
    f4 acc = {0.f, 0.f, 0.f, 0.f};
#pragma unroll
    for (int k0 = 0; k0 < 544; k0 += 32) {
      bfrag a = *(const bfrag*)(arow + k0 + q8);
      bfrag b = *(const bfrag*)(brow + k0 + q8);
      acc = __builtin_amdgcn_mfma_f32_16x16x32_bf16(a, b, acc, 0, 0, 0);
    }
    // lanes 0..15 hold score[h=0] in acc[0], score[h=1] in acc[1] (col = lane)
    float sc0 = -1e30f, sc1 = -1e30f;
    if (lane < KK) {
      sc0 = (acc[0] + s_qbk[0]) * 0.07624928516630234f;  // 1/sqrt(172)
      sc1 = (acc[1] + s_qbk[1]) * 0.07624928516630234f;
      if (s_nb[lane] == 0) { sc0 = -1e9f; sc1 = -1e9f; }
    }
    float m0 = sc0, m1 = sc1;
#pragma unroll
    for (int d = 1; d < 16; d <<= 1) {
      m0 = fmaxf(m0, __shfl_xor(m0, d, 16));
      m1 = fmaxf(m1, __shfl_xor(m1, d, 16));
    }
    float e0 = (lane < KK) ? expf(sc0 - m0) : 0.f;
    float e1 = (lane < KK) ? expf(sc1 - m1) : 0.f;
    float u0 = e0, u1 = e1;
#pragma unroll
    for (int d = 1; d < 16; d <<= 1) {
      u0 += __shfl_xor(u0, d, 16);
      u1 += __shfl_xor(u1, d, 16);
    }
    if (lane < 16) { s_att[0][lane] = e0 / u0; s_att[1][lane] = e1 / u1; }
  }
  __syncthreads();

  // ---- phase 4: c vector, both heads per kin read ----
  unsigned short* Crow = C + (size_t)i * CK;
  if (t < 129) {
    const int x = t * 4;
    f4 a0 = {0.f,0.f,0.f,0.f}, a1 = {0.f,0.f,0.f,0.f};
#pragma unroll
    for (int k = 0; k < KK; k++) {
      us4 v = *(const us4*)&s_kin[k][x];
      float w0 = s_att[0][k], w1 = s_att[1][k];
#pragma unroll
      for (int j = 0; j < 4; j++) {
        float f = b2f(v[j]);
        a0[j] += w0 * f;
        a1[j] += w1 * f;
      }
    }
    us4 o0, o1;
#pragma unroll
    for (int j = 0; j < 4; j++) { o0[j] = f2b(a0[j]); o1[j] = f2b(a1[j]); }
    *(us4*)(Crow + x) = o0;
    *(us4*)(Crow + 516 + x) = o1;
  } else if (t < 143) {
    us4 z = {0,0,0,0};
    *(us4*)(Crow + 1032 + (t - 129) * 4) = z;
  }
}

// mrgA row = [allmask? 0 : o2 (344) | src_feat (172) | 0], bf16 stride 576
__global__ __launch_bounds__(192) void build_mrgA(
    const unsigned short* o2 /*ld 384*/, const int* nbA, const int* nbB, int split,
    const unsigned short* srcf, int ld_src, unsigned short* mrgA) {
  const int i = blockIdx.x, t = threadIdx.x;
  const int* nbp = (i < split) ? nbA + (size_t)i*KK : nbB + (size_t)(i - split)*KK;
  __shared__ int allm;
  if (t == 0) {
    int a = 1;
    for (int k = 0; k < KK; k++) if (nbp[k] != 0) a = 0;
    allm = a;
  }
  __syncthreads();
  if (t >= 144) return;
  unsigned short* row = mrgA + (size_t)i * KIN_K;
  if (t < 86) {
    const int c = t * 4;
    us4 v = {0,0,0,0};
    if (!allm) v = *(const us4*)(o2 + (size_t)i*QIN_K + c);
    *(us4*)(row + c) = v;
  } else if (t < 129) {
    const int c = (t - 86) * 4;
    *(us4*)(row + 344 + c) = *(const us4*)(srcf + (size_t)i*ld_src + c);
  } else {
    us4 z = {0,0,0,0};
    *(us4*)(row + 516 + (t - 129) * 4) = z;
  }
}

// ---------------- launch ----------------
extern "C" void kernel_launch(void* const* d_in, const int* in_sizes, int n_in,
                              void* d_out, int out_size, void* d_ws, size_t ws_size,
                              hipStream_t stream) {
  const float* node_features = (const float*)d_in[0];
  const float* edge_features = (const float*)d_in[1];
  const float* memory        = (const float*)d_in[2];
  const float* last_update   = (const float*)d_in[3];
  const float* time_w        = (const float*)d_in[4];
  const float* time_b        = (const float*)d_in[5];
  const float* num_w1 = (const float*)d_in[6];
  const float* num_b1 = (const float*)d_in[7];
  const float* num_w2 = (const float*)d_in[8];
  const float* num_b2 = (const float*)d_in[9];
  const float* msg_w1 = (const float*)d_in[10];
  const float* msg_b1 = (const float*)d_in[11];
  const float* msg_w2 = (const float*)d_in[12];
  const float* msg_b2 = (const float*)d_in[13];
  const float* gru_wih = (const float*)d_in[14];
  const float* gru_whh = (const float*)d_in[15];
  const float* gru_bih = (const float*)d_in[16];
  const float* gru_bhh = (const float*)d_in[17];
  const float* att_wq = (const float*)d_in[18];
  const float* att_wk = (const float*)d_in[19];
  const float* att_wv = (const float*)d_in[20];
  const float* att_bq = (const float*)d_in[21];
  const float* att_bk = (const float*)d_in[22];
  const float* att_bv = (const float*)d_in[23];
  const float* att_wo = (const float*)d_in[24];
  const float* att_bo = (const float*)d_in[25];
  const float* mrg_w1 = (const float*)d_in[26];
  const float* mrg_b1 = (const float*)d_in[27];
  const float* mrg_w2 = (const float*)d_in[28];
  const float* mrg_b2 = (const float*)d_in[29];
  const float* edge_times = (const float*)d_in[30];
  const float* num_conn   = (const float*)d_in[31];
  const float* n1_et = (const float*)d_in[32];
  const float* n2_et = (const float*)d_in[33];
  const int* src = (const int*)d_in[34];
  const int* dst = (const int*)d_in[35];
  const int* neg = (const int*)d_in[36];
  const int* edge_idxs = (const int*)d_in[37];
  const int* n1_nb   = (const int*)d_in[38];
  const int* n1_eidx = (const int*)d_in[39];
  const int* n2_nb   = (const int*)d_in[40];
  const int* n2_eidx = (const int*)d_in[41];

  // ---- workspace (persistent ~42.5MB + transient region ~23MB) ----
  char* ws = (char*)d_ws;
  size_t off = 0;
  auto alloc = [&](size_t b) -> char* {
    char* p = ws + off; off = (off + b + 255) & ~(size_t)255; return p;
  };
  int* map  = (int*)alloc((size_t)NN * 4);
  float* upd = (float*)alloc((size_t)2*BB*DD * 4);
  unsigned short* wqh_b = (unsigned short*)alloc((size_t)SZ_WQH * 2);
  unsigned short* wkh_b = (unsigned short*)alloc((size_t)SZ_WKH * 2);
  unsigned short* wvh_b = (unsigned short*)alloc((size_t)SZ_WVH * 2);
  unsigned short* woT_b = (unsigned short*)alloc((size_t)SZ_WOT * 2);
  unsigned short* wm1_t = (unsigned short*)alloc((size_t)SZ_M1 * 2);
  unsigned short* wm2_t = (unsigned short*)alloc((size_t)SZ_M2 * 2);
  unsigned short* msgw1t = (unsigned short*)alloc((size_t)SZ_MW1 * 2);
  unsigned short* msgw2t = (unsigned short*)alloc((size_t)SZ_MW2 * 2);
  unsigned short* gruwih_b = (unsigned short*)alloc((size_t)SZ_GIH * 2);
  unsigned short* gruwhh_b = (unsigned short*)alloc((size_t)SZ_GHH * 2);
  unsigned short* Gcat = (unsigned short*)alloc((size_t)2*GROWS*384 * 2);
  unsigned short* Mcat = (unsigned short*)alloc((size_t)2*384*CK * 2);
  float* bqk  = (float*)alloc((size_t)2*QKLD * 4);
  float* bvwo = (float*)alloc((size_t)2*344 * 4);
  unsigned short* costb = (unsigned short*)alloc((size_t)256 * 2);
  unsigned short* qin0 = (unsigned short*)alloc((size_t)R0P*QIN_K * 2);
  unsigned short* Cbuf = (unsigned short*)alloc((size_t)R0P*CK * 2);   // C0, later C1
  unsigned short* conv0 = (unsigned short*)alloc((size_t)R0P*DD * 2);

  char* T = ws + off;  // transient region, phases stream-serialized
  // msg phase overlay
  size_t mo = 0;
  auto ma = [&](size_t b) -> char* { char* p = T + mo; mo = (mo + b + 255) & ~(size_t)255; return p; };
  unsigned short* raw  = (unsigned short*)ma((size_t)640*704 * 2);
  unsigned short* memb = (unsigned short*)ma((size_t)640*192 * 2);
  unsigned short* h1m  = (unsigned short*)ma((size_t)640*384 * 2);
  unsigned short* msgb = (unsigned short*)ma((size_t)640*128 * 2);
  float* gi = (float*)ma((size_t)600*516 * 4);
  float* gh = (float*)ma((size_t)600*516 * 4);
  // qk0 overlay (after gru_gate)
  unsigned short* qk0 = (unsigned short*)T;                            // R0P*QKLD*2 = 20.8MB
  // o2/merge overlay (after attn_core<0>)
  size_t oo = 0;
  auto oa = [&](size_t b) -> char* { char* p = T + oo; oo = (oo + b + 255) & ~(size_t)255; return p; };
  unsigned short* o2_0  = (unsigned short*)oa((size_t)R0P*QIN_K * 2);
  unsigned short* mrgA0 = (unsigned short*)oa((size_t)R0P*KIN_K * 2);
  unsigned short* h0    = (unsigned short*)oa((size_t)R0P*H_K * 2);
  // layer-1 overlay (after conv0 written)
  size_t lo = 0;
  auto la = [&](size_t b) -> char* { char* p = T + lo; lo = (lo + b + 255) & ~(size_t)255; return p; };
  unsigned short* qin1  = (unsigned short*)la((size_t)L1P*QIN_K * 2);
  unsigned short* qk1   = (unsigned short*)la((size_t)L1P*QKLD * 2);
  unsigned short* o2_1  = (unsigned short*)la((size_t)L1P*QIN_K * 2);
  unsigned short* mrgA1 = (unsigned short*)la((size_t)L1P*KIN_K * 2);
  unsigned short* h1b   = (unsigned short*)la((size_t)L1P*H_K * 2);

  // ---- phase A: map + weight preps ----
  fill_map<<<(NN + 255)/256, 256, 0, stream>>>(map);
  set_map<<<(BB + 63)/64, 64, 0, stream>>>(map, src, dst);
  {
    long tot = (long)SZ_WQH + SZ_WKH + SZ_WVH + SZ_WOT + SZ_M1 + SZ_M2 + SZ_MW1 + SZ_MW2 + SZ_GIH + SZ_GHH;
    prep_w<<<(int)((tot + 255)/256), 256, 0, stream>>>(
        att_wq, att_wk, att_wv, att_wo, mrg_w1, mrg_w2, msg_w1, msg_w2, gru_wih, gru_whh,
        wqh_b, wkh_b, wvh_b, woT_b, wm1_t, wm2_t, msgw1t, msgw2t, gruwih_b, gruwhh_b);
    long tb = (long)SB_QK + SB_VO + SB_GV + SB_CT;
    prep_bias<<<(int)((tb + 255)/256), 256, 0, stream>>>(
        att_wq, att_wk, att_wo, att_bq, att_bk, att_bv, att_bo, time_b, bqk, bvwo, Gcat, costb);
  }
  // G gemms: Gcat rows [h*516 + x][y] = sum_d Wk[x][hd] Wq[y][hd]
  for (int l = 0; l < 2; l++)
    for (int h = 0; h < 2; h++)
      gemm128<true, false><<<dim3(5, 3), 256, 0, stream>>>(
          wkh_b + (size_t)(l*2+h)*640*192, 192,
          wqh_b + (size_t)(l*2+h)*384*192, 192, nullptr,
          Gcat + (size_t)l*GROWS*384 + (size_t)h*516*384, 384, 516, 344, 384, 192);
  // Mcat gemms: Mcat[j][h*516+x] = sum_d Wo[hd][j] Wv[x][hd]
  for (int l = 0; l < 2; l++)
    for (int h = 0; h < 2; h++)
      gemm128<true, false><<<dim3(3, 5), 256, 0, stream>>>(
          woT_b + (size_t)(l*2+h)*384*192, 192,
          wvh_b + (size_t)(l*2+h)*640*192, 192, nullptr,
          Mcat + (size_t)l*384*CK + (size_t)h*516, CK, 344, 516, (h == 0 ? 516 : 572), 192);

  // ---- phase B: message + GRU memory update (GEMM-ified) ----
  build_raw<<<2*BB, 256, 0, stream>>>(
      memory, edge_features, last_update, time_w, time_b,
      num_w1, num_b1, num_w2, num_b2, edge_times, num_conn,
      src, dst, edge_idxs, raw, memb);
  gemm128<true, true><<<dim3(5, 3), 256, 0, stream>>>(
      raw, 704, msgw1t, 704, msg_b1, h1m, 384, 600, 344, 384, 704);
  gemm128<true, false><<<dim3(5, 1), 256, 0, stream>>>(
      h1m, 384, msgw2t, 384, msg_b2, msgb, 128, 600, 100, 128, 384);
  gemm128<false, false><<<dim3(5, 5), 256, 0, stream>>>(
      msgb, 128, gruwih_b, 128, gru_bih, gi, 516, 600, 516, 516, 128);
  gemm128<false, false><<<dim3(5, 5), 256, 0, stream>>>(
      memb, 192, gruwhh_b, 192, gru_bhh, gh, 516, 600, 516, 516, 192);
  gru_gate<<<2*BB, 192, 0, stream>>>(gi, gh, memory, src, dst, upd);

  // ---- layer-0 ----
  build_qin0<<<R0T, 128, 0, stream>>>(src, dst, neg, n1_nb, memory, upd, map,
                                      node_features, costb, qin0);
  gemm128<true, false><<<dim3(R0P/128, 9), 256, 0, stream>>>(
      qin0, QIN_K, Gcat, 384, bqk, qk0, QKLD, R0T, QKN, QKN, QIN_K);
  attn_core<0><<<R0T, 256, 0, stream>>>(
      qk0, n1_nb, n1_eidx, n1_et, n2_nb, n2_eidx, n2_et, edge_times,
      memory, upd, map, node_features, qin0, QIN_K,
      edge_features, time_w, time_b, Cbuf);
  gemm128<true, false><<<dim3(R0P/128, 3), 256, 0, stream>>>(
      Cbuf, CK, Mcat, CK, bvwo, o2_0, QIN_K, R0T, 344, 344, CK);
  build_mrgA<<<R0T, 192, 0, stream>>>(o2_0, n1_nb, n2_nb, 3*BB, qin0, QIN_K, mrgA0);
  gemm128<true, true><<<dim3(R0P/128, 2), 256, 0, stream>>>(
      mrgA0, KIN_K, wm1_t, KIN_K, mrg_b1, h0, H_K, R0T, 172, 192, KIN_K);
  gemm128<true, false><<<dim3(R0P/128, 2), 256, 0, stream>>>(
      h0, H_K, wm2_t, H_K, mrg_b2, conv0, DD, R0T, 172, 172, H_K);

  // ---- layer-1 ----
  build_qin1<<<3*BB, 128, 0, stream>>>(conv0, costb, qin1);
  gemm128<true, false><<<dim3(L1P/128, 9), 256, 0, stream>>>(
      qin1, QIN_K, Gcat + (size_t)GROWS*384, 384, bqk + QKLD, qk1, QKLD, 3*BB, QKN, QKN, QIN_K);
  attn_core<1><<<3*BB, 256, 0, stream>>>(
      qk1, n1_nb, n1_eidx, n1_et, n1_nb, n1_eidx, n1_et, edge_times,
      memory, upd, map, node_features, conv0, DD,
      edge_features, time_w, time_b, Cbuf);
  gemm128<true, false><<<dim3(L1P/128, 3), 256, 0, stream>>>(
      Cbuf, CK, Mcat + (size_t)384*CK, CK, bvwo + 344, o2_1, QIN_K, 3*BB, 344, 344, CK);
  build_mrgA<<<3*BB, 192, 0, stream>>>(o2_1, n1_nb, n1_nb, 3*BB, conv0, DD, mrgA1);
  gemm128<true, true><<<dim3(L1P/128, 2), 256, 0, stream>>>(
      mrgA1, KIN_K, wm1_t + (size_t)256*KIN_K, KIN_K, mrg_b1 + 172, h1b, H_K, 3*BB, 172, 192, KIN_K);
  gemm128<false, false><<<dim3(L1P/128, 2), 256, 0, stream>>>(
      h1b, H_K, wm2_t + (size_t)256*H_K, H_K, mrg_b2 + 172, (float*)d_out, DD, 3*BB, 172, 172, H_K);
}